// Round 1
// baseline (2624.610 us; speedup 1.0000x reference)
//
#include <hip/hip_runtime.h>

#define BB 4
#define SS 2048
#define HH 16
#define DD 64
#define TQ 64
#define TK 64
#define SP 68           // padded LDS row stride (floats)
#define NKT (SS / TK)   // 32 k-tiles

#define FMA4(accrow, s, v4) do { \
    accrow[0] += (s) * (v4).x;   \
    accrow[1] += (s) * (v4).y;   \
    accrow[2] += (s) * (v4).z;   \
    accrow[3] += (s) * (v4).w;   \
} while (0)

// Score tile: c[jj][mm] = sum_d Qs[ty*4+jj][d] * K[tx*4+mm][d]
// KsT is K transposed in LDS: KsT[d*SP + m]
__device__ __forceinline__ void score_tile(const float* Qs, const float* KsT,
                                           int tx, int ty, float c[4][4]) {
    #pragma unroll
    for (int jj = 0; jj < 4; jj++) { c[jj][0]=0.f; c[jj][1]=0.f; c[jj][2]=0.f; c[jj][3]=0.f; }
    #pragma unroll 4
    for (int d0 = 0; d0 < DD; d0 += 4) {
        float4 qr[4], kr[4];
        #pragma unroll
        for (int jj = 0; jj < 4; jj++)
            qr[jj] = *(const float4*)(Qs + (ty*4+jj)*SP + d0);
        #pragma unroll
        for (int di = 0; di < 4; di++)
            kr[di] = *(const float4*)(KsT + (d0+di)*SP + tx*4);
        #pragma unroll
        for (int jj = 0; jj < 4; jj++) {
            FMA4(c[jj], qr[jj].x, kr[0]);
            FMA4(c[jj], qr[jj].y, kr[1]);
            FMA4(c[jj], qr[jj].z, kr[2]);
            FMA4(c[jj], qr[jj].w, kr[3]);
        }
    }
}

__global__ __launch_bounds__(256, 2)
void attn_fp32(const float* __restrict__ q, const float* __restrict__ k,
               const float* __restrict__ v, float* __restrict__ out,
               float* __restrict__ attn) {
    __shared__ float Qs[TQ * SP];
    __shared__ float KsT[DD * SP];
    __shared__ float Vs[TK * SP];
    __shared__ float Ps[TQ * SP];

    const int idx = blockIdx.x;
    const int qt = idx & (NKT - 1);
    const int bh = idx >> 5;          // b*H + h
    const int h  = bh & (HH - 1);
    const int b  = bh >> 4;
    const int q0 = qt * TQ;

    const int t  = threadIdx.x;
    const int tx = t & 15;
    const int ty = t >> 4;

    const int lr = t >> 2;            // 0..63: tile row for cooperative loads
    const int lc = (t & 3) * 16;      // 0,16,32,48

    // ---- load Q tile (pre-scaled by 1/TEMPERATURE) ----
    {
        const float* gq = q + ((size_t)((b*SS + q0 + lr)*HH + h))*DD + lc;
        float* sq = Qs + lr*SP + lc;
        #pragma unroll
        for (int i = 0; i < 4; i++) {
            float4 val = *(const float4*)(gq + i*4);
            val.x *= 0.125f; val.y *= 0.125f; val.z *= 0.125f; val.w *= 0.125f;
            *(float4*)(sq + i*4) = val;
        }
    }

    float m_run[4], l_run[4];
    #pragma unroll
    for (int jj = 0; jj < 4; jj++) { m_run[jj] = -3.0e38f; l_run[jj] = 0.0f; }

    const int ntile = qt + 1;

    // ---- phase 1: row max & sumexp (online) ----
    for (int kt = 0; kt < ntile; kt++) {
        const int m0 = kt * TK;
        __syncthreads();
        {   // K tile, transposed into LDS
            const float* gk = k + ((size_t)((b*SS + m0 + lr)*HH + h))*DD + lc;
            #pragma unroll
            for (int i = 0; i < 4; i++) {
                float4 kv = *(const float4*)(gk + i*4);
                KsT[(lc+i*4+0)*SP + lr] = kv.x;
                KsT[(lc+i*4+1)*SP + lr] = kv.y;
                KsT[(lc+i*4+2)*SP + lr] = kv.z;
                KsT[(lc+i*4+3)*SP + lr] = kv.w;
            }
        }
        __syncthreads();

        float c[4][4];
        score_tile(Qs, KsT, tx, ty, c);
        if (kt == qt) {   // diagonal tile: q0 == m0, local compare valid
            #pragma unroll
            for (int jj = 0; jj < 4; jj++)
                #pragma unroll
                for (int mm = 0; mm < 4; mm++)
                    if (tx*4+mm > ty*4+jj) c[jj][mm] = -1.0e9f;
        }
        #pragma unroll
        for (int jj = 0; jj < 4; jj++) {
            float tm = fmaxf(fmaxf(c[jj][0], c[jj][1]), fmaxf(c[jj][2], c[jj][3]));
            tm = fmaxf(tm, __shfl_xor(tm, 1));
            tm = fmaxf(tm, __shfl_xor(tm, 2));
            tm = fmaxf(tm, __shfl_xor(tm, 4));
            tm = fmaxf(tm, __shfl_xor(tm, 8));
            float ts = __expf(c[jj][0]-tm) + __expf(c[jj][1]-tm)
                     + __expf(c[jj][2]-tm) + __expf(c[jj][3]-tm);
            ts += __shfl_xor(ts, 1);
            ts += __shfl_xor(ts, 2);
            ts += __shfl_xor(ts, 4);
            ts += __shfl_xor(ts, 8);
            float nm = fmaxf(m_run[jj], tm);
            l_run[jj] = l_run[jj]*__expf(m_run[jj]-nm) + ts*__expf(tm-nm);
            m_run[jj] = nm;
        }
    }

    float mf[4], rl[4];
    #pragma unroll
    for (int jj = 0; jj < 4; jj++) { mf[jj] = m_run[jj]; rl[jj] = 1.0f / l_run[jj]; }

    float acc[4][4];
    #pragma unroll
    for (int jj = 0; jj < 4; jj++) { acc[jj][0]=0.f; acc[jj][1]=0.f; acc[jj][2]=0.f; acc[jj][3]=0.f; }

    const size_t arow = (size_t)bh * SS;   // attn row-block base (rows)

    // ---- phase 2: recompute scores, write attn, accumulate PV ----
    for (int kt = 0; kt < NKT; kt++) {
        const int m0 = kt * TK;
        if (kt >= ntile) {
            // fully-masked tile: write zeros (d_out is poisoned each call)
            const float4 z4 = make_float4(0.f, 0.f, 0.f, 0.f);
            #pragma unroll
            for (int jj = 0; jj < 4; jj++)
                *(float4*)(attn + (arow + q0 + ty*4 + jj)*SS + m0 + tx*4) = z4;
            continue;
        }
        __syncthreads();
        {   // K tile (transposed) + V tile (row-major)
            const float* gk = k + ((size_t)((b*SS + m0 + lr)*HH + h))*DD + lc;
            #pragma unroll
            for (int i = 0; i < 4; i++) {
                float4 kv = *(const float4*)(gk + i*4);
                KsT[(lc+i*4+0)*SP + lr] = kv.x;
                KsT[(lc+i*4+1)*SP + lr] = kv.y;
                KsT[(lc+i*4+2)*SP + lr] = kv.z;
                KsT[(lc+i*4+3)*SP + lr] = kv.w;
            }
            const float* gv = v + ((size_t)((b*SS + m0 + lr)*HH + h))*DD + lc;
            float* sv = Vs + lr*SP + lc;
            #pragma unroll
            for (int i = 0; i < 4; i++)
                *(float4*)(sv + i*4) = *(const float4*)(gv + i*4);
        }
        __syncthreads();

        float c[4][4];
        score_tile(Qs, KsT, tx, ty, c);
        if (kt == qt) {
            #pragma unroll
            for (int jj = 0; jj < 4; jj++)
                #pragma unroll
                for (int mm = 0; mm < 4; mm++)
                    if (tx*4+mm > ty*4+jj) c[jj][mm] = -1.0e9f;
        }

        #pragma unroll
        for (int jj = 0; jj < 4; jj++) {
            float4 pv;
            pv.x = __expf(c[jj][0] - mf[jj]) * rl[jj];
            pv.y = __expf(c[jj][1] - mf[jj]) * rl[jj];
            pv.z = __expf(c[jj][2] - mf[jj]) * rl[jj];
            pv.w = __expf(c[jj][3] - mf[jj]) * rl[jj];
            *(float4*)(attn + (arow + q0 + ty*4 + jj)*SS + m0 + tx*4) = pv;
            *(float4*)(Ps + (ty*4+jj)*SP + tx*4) = pv;
        }
        __syncthreads();

        // PV: acc[jj][dd] += sum_m P[j][m] * V[m][d]
        #pragma unroll 4
        for (int mq = 0; mq < 16; mq++) {
            float4 pr[4], vr[4];
            #pragma unroll
            for (int jj = 0; jj < 4; jj++)
                pr[jj] = *(const float4*)(Ps + (ty*4+jj)*SP + mq*4);
            #pragma unroll
            for (int mi = 0; mi < 4; mi++)
                vr[mi] = *(const float4*)(Vs + (mq*4+mi)*SP + tx*4);
            #pragma unroll
            for (int jj = 0; jj < 4; jj++) {
                FMA4(acc[jj], pr[jj].x, vr[0]);
                FMA4(acc[jj], pr[jj].y, vr[1]);
                FMA4(acc[jj], pr[jj].z, vr[2]);
                FMA4(acc[jj], pr[jj].w, vr[3]);
            }
        }
    }

    // ---- write out[b, j, h, d] ----
    #pragma unroll
    for (int jj = 0; jj < 4; jj++) {
        float4 o;
        o.x = acc[jj][0]; o.y = acc[jj][1]; o.z = acc[jj][2]; o.w = acc[jj][3];
        *(float4*)(out + ((size_t)((b*SS + q0 + ty*4 + jj)*HH + h))*DD + tx*4) = o;
    }
}

extern "C" void kernel_launch(void* const* d_in, const int* in_sizes, int n_in,
                              void* d_out, int out_size, void* d_ws, size_t ws_size,
                              hipStream_t stream) {
    (void)in_sizes; (void)n_in; (void)out_size; (void)d_ws; (void)ws_size;
    const float* q = (const float*)d_in[0];
    const float* k = (const float*)d_in[1];
    const float* v = (const float*)d_in[2];
    // d_in[3] is the causal mask; causality is hard-coded.
    float* out  = (float*)d_out;
    float* attn = out + (size_t)BB * SS * HH * DD;

    dim3 grid(BB * HH * NKT);   // 2048 blocks: (b,h) x 32 q-tiles
    dim3 block(256);
    attn_fp32<<<grid, block, 0, stream>>>(q, k, v, out, attn);
}